// Round 1
// baseline (613.662 us; speedup 1.0000x reference)
//
#include <hip/hip_runtime.h>
#include <math.h>

#define N_ENT 100000
#define N_REL 64
#define DIM   128
#define KNB   32
#define BATCH 16384

// broadcast a float from a given lane of the wave (uniform lane index)
__device__ __forceinline__ float lane_bcast(float v, int lane) {
    return __int_as_float(__builtin_amdgcn_readlane(__float_as_int(v), lane));
}

// ---------------------------------------------------------------------------
// Kernel A: ENT_TR[e][j] = maxnorm(ent[e]) @ Wr^T + Wr_b ; SCALE[e] = norm scale
// 128 threads (thread j = output dim), Wr row j register-resident (128 VGPRs),
// input row wave-distributed + v_readlane broadcast. 32 rows per block.
// ---------------------------------------------------------------------------
__global__ __launch_bounds__(128) void k_ent_pre(
    const float* __restrict__ ent, const float* __restrict__ Wr,
    const float* __restrict__ Wrb, float* __restrict__ ENT_TR,
    float* __restrict__ SCALE)
{
    const int tid  = threadIdx.x;   // output dim j
    const int lane = tid & 63;
    float w[DIM];
    #pragma unroll
    for (int i = 0; i < DIM; ++i) w[i] = Wr[tid * DIM + i];
    const float bj = Wrb[tid];

    const int row0 = blockIdx.x * 32;
    for (int r = 0; r < 32; ++r) {
        const int row = row0 + r;
        const float xa = ent[(size_t)row * DIM + lane];
        const float xb = ent[(size_t)row * DIM + 64 + lane];
        // row L2 norm (each wave reduces over the full row it holds)
        float ss = xa * xa + xb * xb;
        #pragma unroll
        for (int m = 1; m < 64; m <<= 1) ss += __shfl_xor(ss, m);
        const float nrm = sqrtf(ss);
        const float s = fminf(1.0f, 1.0f / fmaxf(nrm, 1e-12f));
        // dot(x, Wr_row_j) via readlane broadcast
        float acc = 0.0f;
        #pragma unroll
        for (int i = 0; i < 64; ++i) acc = fmaf(lane_bcast(xa, i), w[i], acc);
        #pragma unroll
        for (int i = 0; i < 64; ++i) acc = fmaf(lane_bcast(xb, i), w[64 + i], acc);
        ENT_TR[(size_t)row * DIM + tid] = fmaf(acc, s, bj);
        if (tid == 0) SCALE[row] = s;
    }
}

// ---------------------------------------------------------------------------
// Kernel A2: REL_N = maxnorm(rel_table) (64 rows)
// ---------------------------------------------------------------------------
__global__ __launch_bounds__(128) void k_rel_pre(
    const float* __restrict__ rel, float* __restrict__ REL_N)
{
    __shared__ float part[2];
    const int row = blockIdx.x, tid = threadIdx.x;
    const float x = rel[row * DIM + tid];
    float ss = x * x;
    #pragma unroll
    for (int m = 1; m < 64; m <<= 1) ss += __shfl_xor(ss, m);
    if ((tid & 63) == 0) part[tid >> 6] = ss;
    __syncthreads();
    const float tot = part[0] + part[1];
    const float s = fminf(1.0f, 1.0f / fmaxf(sqrtf(tot), 1e-12f));
    REL_N[row * DIM + tid] = x * s;
}

// ---------------------------------------------------------------------------
// Kernel B: per batch element: gather hr/h, 32 (tr, r) rows, score = sum_j
// tanh(hr+r)*tr, softmax over k, Nh = sum att*t, write U = h+Nh, V = h*Nh.
// One block (256 threads) per batch element.
// ---------------------------------------------------------------------------
__global__ __launch_bounds__(256) void k_main(
    const int* __restrict__ idx, const int* __restrict__ adj_ent,
    const int* __restrict__ adj_rel, const float* __restrict__ ent,
    const float* __restrict__ ENT_TR, const float* __restrict__ SCALE,
    const float* __restrict__ REL_N, float* __restrict__ U,
    float* __restrict__ V)
{
    __shared__ float hr_s[DIM], h_s[DIM], sc_s[KNB], att_s[KNB], scl_s[KNB];
    __shared__ int eid_s[KNB], rid_s[KNB];

    const int b = blockIdx.x;
    const int tid = threadIdx.x;
    int id = idx[b];
    id = id < 0 ? 0 : (id > N_ENT - 1 ? N_ENT - 1 : id);

    if (tid < DIM) {
        hr_s[tid] = ENT_TR[(size_t)id * DIM + tid];
        h_s[tid]  = ent[(size_t)id * DIM + tid] * SCALE[id];
    }
    if (tid < KNB) {
        const int e = adj_ent[(size_t)id * KNB + tid];
        eid_s[tid] = e;
        rid_s[tid] = adj_rel[(size_t)id * KNB + tid];
        scl_s[tid] = SCALE[e];
    }
    __syncthreads();

    // score_k = sum_j tanh(hr[j] + r_k[j]) * tr_k[j]; 8 threads per k
    {
        const int k = tid >> 3, s8 = tid & 7;
        const float* trp = ENT_TR + (size_t)eid_s[k] * DIM + s8 * 16;
        const float* rp  = REL_N + rid_s[k] * DIM + s8 * 16;
        const float* hp  = hr_s + s8 * 16;
        float p = 0.0f;
        #pragma unroll
        for (int t = 0; t < 16; ++t)
            p += tanhf(hp[t] + rp[t]) * trp[t];
        p += __shfl_xor(p, 1);
        p += __shfl_xor(p, 2);
        p += __shfl_xor(p, 4);
        if (s8 == 0) sc_s[k] = p;
    }
    __syncthreads();

    // softmax over k (lanes 0..31 of wave 0)
    if (tid < KNB) {
        const float s = sc_s[tid];
        float m = s;
        #pragma unroll
        for (int mk = 1; mk < 32; mk <<= 1) m = fmaxf(m, __shfl_xor(m, mk));
        const float e = expf(s - m);
        float t = e;
        #pragma unroll
        for (int mk = 1; mk < 32; mk <<= 1) t += __shfl_xor(t, mk);
        att_s[tid] = e / t;
    }
    __syncthreads();

    // Nh, U, V
    if (tid < DIM) {
        float nh = 0.0f;
        #pragma unroll 4
        for (int k = 0; k < KNB; ++k)
            nh = fmaf(att_s[k] * scl_s[k], ent[(size_t)eid_s[k] * DIM + tid], nh);
        const float h = h_s[tid];
        U[(size_t)b * DIM + tid] = h + nh;
        V[(size_t)b * DIM + tid] = h * nh;
    }
}

// ---------------------------------------------------------------------------
// Kernel C1: out = leaky(U @ W1^T + b1)      (readlane matvec, 32 rows/block)
// Kernel C2: out += leaky(V @ W2^T + b2)
// ---------------------------------------------------------------------------
__global__ __launch_bounds__(128) void k_out1(
    const float* __restrict__ X, const float* __restrict__ W,
    const float* __restrict__ bias, float* __restrict__ out)
{
    const int tid = threadIdx.x, lane = tid & 63;
    float w[DIM];
    #pragma unroll
    for (int i = 0; i < DIM; ++i) w[i] = W[tid * DIM + i];
    const float bj = bias[tid];
    const int row0 = blockIdx.x * 32;
    for (int r = 0; r < 32; ++r) {
        const int row = row0 + r;
        const float xa = X[(size_t)row * DIM + lane];
        const float xb = X[(size_t)row * DIM + 64 + lane];
        float acc = bj;
        #pragma unroll
        for (int i = 0; i < 64; ++i) acc = fmaf(lane_bcast(xa, i), w[i], acc);
        #pragma unroll
        for (int i = 0; i < 64; ++i) acc = fmaf(lane_bcast(xb, i), w[64 + i], acc);
        out[(size_t)row * DIM + tid] = acc > 0.0f ? acc : 0.2f * acc;
    }
}

__global__ __launch_bounds__(128) void k_out2(
    const float* __restrict__ X, const float* __restrict__ W,
    const float* __restrict__ bias, float* __restrict__ out)
{
    const int tid = threadIdx.x, lane = tid & 63;
    float w[DIM];
    #pragma unroll
    for (int i = 0; i < DIM; ++i) w[i] = W[tid * DIM + i];
    const float bj = bias[tid];
    const int row0 = blockIdx.x * 32;
    for (int r = 0; r < 32; ++r) {
        const int row = row0 + r;
        const float xa = X[(size_t)row * DIM + lane];
        const float xb = X[(size_t)row * DIM + 64 + lane];
        float acc = bj;
        #pragma unroll
        for (int i = 0; i < 64; ++i) acc = fmaf(lane_bcast(xa, i), w[i], acc);
        #pragma unroll
        for (int i = 0; i < 64; ++i) acc = fmaf(lane_bcast(xb, i), w[64 + i], acc);
        const float l = acc > 0.0f ? acc : 0.2f * acc;
        out[(size_t)row * DIM + tid] += l;
    }
}

extern "C" void kernel_launch(void* const* d_in, const int* in_sizes, int n_in,
                              void* d_out, int out_size, void* d_ws, size_t ws_size,
                              hipStream_t stream) {
    (void)in_sizes; (void)n_in; (void)out_size; (void)ws_size;
    const int*   idx     = (const int*)d_in[0];
    const int*   adj_ent = (const int*)d_in[1];
    const int*   adj_rel = (const int*)d_in[2];
    const float* ent     = (const float*)d_in[3];
    const float* rel     = (const float*)d_in[4];
    const float* Wr_w    = (const float*)d_in[5];
    const float* Wr_b    = (const float*)d_in[6];
    const float* W1_w    = (const float*)d_in[7];
    const float* W1_b    = (const float*)d_in[8];
    const float* W2_w    = (const float*)d_in[9];
    const float* W2_b    = (const float*)d_in[10];
    float* out = (float*)d_out;

    char* ws = (char*)d_ws;
    // workspace layout (bytes): ENT_TR 51.2MB | SCALE 0.4MB | REL_N 32KB | U 8.39MB | V 8.39MB
    float* ENT_TR = (float*)(ws);
    float* SCALE  = (float*)(ws + 51200000);
    float* REL_N  = (float*)(ws + 51600000);
    float* U      = (float*)(ws + 51632768);
    float* V      = (float*)(ws + 60021376);

    k_ent_pre<<<dim3(N_ENT / 32), dim3(128), 0, stream>>>(ent, Wr_w, Wr_b, ENT_TR, SCALE);
    k_rel_pre<<<dim3(N_REL), dim3(128), 0, stream>>>(rel, REL_N);
    k_main<<<dim3(BATCH), dim3(256), 0, stream>>>(idx, adj_ent, adj_rel, ent,
                                                  ENT_TR, SCALE, REL_N, U, V);
    k_out1<<<dim3(BATCH / 32), dim3(128), 0, stream>>>(U, W1_w, W1_b, out);
    k_out2<<<dim3(BATCH / 32), dim3(128), 0, stream>>>(V, W2_w, W2_b, out);
}

// Round 2
// 473.100 us; speedup vs baseline: 1.2971x; 1.2971x over previous
//
#include <hip/hip_runtime.h>
#include <math.h>

#define N_ENT 100000
#define N_REL 64
#define DIM   128
#define KNB   32
#define BATCH 16384

// broadcast a float from a given lane of the wave (uniform lane index)
__device__ __forceinline__ float lane_bcast(float v, int lane) {
    return __int_as_float(__builtin_amdgcn_readlane(__float_as_int(v), lane));
}

// ---------------------------------------------------------------------------
// Kernel A: ENT_TR[e][j] = maxnorm(ent[e]) @ Wr^T + Wr_b ; SCALE[e] = norm scale
// ---------------------------------------------------------------------------
__global__ __launch_bounds__(128) void k_ent_pre(
    const float* __restrict__ ent, const float* __restrict__ Wr,
    const float* __restrict__ Wrb, float* __restrict__ ENT_TR,
    float* __restrict__ SCALE)
{
    const int tid  = threadIdx.x;   // output dim j
    const int lane = tid & 63;
    float w[DIM];
    #pragma unroll
    for (int i = 0; i < DIM; ++i) w[i] = Wr[tid * DIM + i];
    const float bj = Wrb[tid];

    const int row0 = blockIdx.x * 32;
    for (int r = 0; r < 32; ++r) {
        const int row = row0 + r;
        const float xa = ent[(size_t)row * DIM + lane];
        const float xb = ent[(size_t)row * DIM + 64 + lane];
        float ss = xa * xa + xb * xb;
        #pragma unroll
        for (int m = 1; m < 64; m <<= 1) ss += __shfl_xor(ss, m);
        const float nrm = sqrtf(ss);
        const float s = fminf(1.0f, 1.0f / fmaxf(nrm, 1e-12f));
        float acc = 0.0f;
        #pragma unroll
        for (int i = 0; i < 64; ++i) acc = fmaf(lane_bcast(xa, i), w[i], acc);
        #pragma unroll
        for (int i = 0; i < 64; ++i) acc = fmaf(lane_bcast(xb, i), w[64 + i], acc);
        ENT_TR[(size_t)row * DIM + tid] = fmaf(acc, s, bj);
        if (tid == 0) SCALE[row] = s;
    }
}

// ---------------------------------------------------------------------------
// Kernel A2: REL_N = maxnorm(rel_table) (64 rows)
// ---------------------------------------------------------------------------
__global__ __launch_bounds__(128) void k_rel_pre(
    const float* __restrict__ rel, float* __restrict__ REL_N)
{
    __shared__ float part[2];
    const int row = blockIdx.x, tid = threadIdx.x;
    const float x = rel[row * DIM + tid];
    float ss = x * x;
    #pragma unroll
    for (int m = 1; m < 64; m <<= 1) ss += __shfl_xor(ss, m);
    if ((tid & 63) == 0) part[tid >> 6] = ss;
    __syncthreads();
    const float tot = part[0] + part[1];
    const float s = fminf(1.0f, 1.0f / fmaxf(sqrtf(tot), 1e-12f));
    REL_N[row * DIM + tid] = x * s;
}

// ---------------------------------------------------------------------------
// Kernel B1: scores. One wave per (b,k) pair; 524288 independent waves.
// score = sum_j tanh(hr_b[j] + r[j]) * tr[j], j over 128 dims (2 per lane).
// ---------------------------------------------------------------------------
__global__ __launch_bounds__(256) void k_score(
    const int* __restrict__ idx, const int* __restrict__ adj_ent,
    const int* __restrict__ adj_rel, const float* __restrict__ ENT_TR,
    const float* __restrict__ REL_N, float* __restrict__ scores)
{
    const int wid  = threadIdx.x >> 6;
    const int lane = threadIdx.x & 63;
    const int p = blockIdx.x * 4 + wid;      // pair id
    const int b = p >> 5;
    const int k = p & (KNB - 1);

    int id = idx[b];
    id = id < 0 ? 0 : (id > N_ENT - 1 ? N_ENT - 1 : id);
    const int e = adj_ent[(size_t)id * KNB + k];
    const int r = adj_rel[(size_t)id * KNB + k];

    const float* __restrict__ tr = ENT_TR + (size_t)e * DIM;
    const float* __restrict__ hr = ENT_TR + (size_t)id * DIM;
    const float* __restrict__ rn = REL_N + r * DIM;

    const float tr0 = tr[lane],      tr1 = tr[lane + 64];
    const float hr0 = hr[lane],      hr1 = hr[lane + 64];
    const float rn0 = rn[lane],      rn1 = rn[lane + 64];

    float s = tanhf(hr0 + rn0) * tr0 + tanhf(hr1 + rn1) * tr1;
    #pragma unroll
    for (int m = 1; m < 64; m <<= 1) s += __shfl_xor(s, m);
    if (lane == 0) scores[p] = s;
}

// ---------------------------------------------------------------------------
// Kernel B2: softmax over k + Nh aggregate + U/V. One 128-thread block per b.
// ---------------------------------------------------------------------------
__global__ __launch_bounds__(128) void k_agg(
    const int* __restrict__ idx, const int* __restrict__ adj_ent,
    const float* __restrict__ ent, const float* __restrict__ SCALE,
    const float* __restrict__ scores, float* __restrict__ U,
    float* __restrict__ V)
{
    __shared__ float att_s[KNB];
    __shared__ int   eid_s[KNB];

    const int b = blockIdx.x;
    const int tid = threadIdx.x;
    int id = idx[b];
    id = id < 0 ? 0 : (id > N_ENT - 1 ? N_ENT - 1 : id);

    if (tid < KNB) {
        const float s = scores[b * KNB + tid];
        float m = s;
        #pragma unroll
        for (int mk = 1; mk < 32; mk <<= 1) m = fmaxf(m, __shfl_xor(m, mk));
        const float e = expf(s - m);
        float t = e;
        #pragma unroll
        for (int mk = 1; mk < 32; mk <<= 1) t += __shfl_xor(t, mk);
        const int eid = adj_ent[(size_t)id * KNB + tid];
        att_s[tid] = (e / t) * SCALE[eid];
        eid_s[tid] = eid;
    }
    __syncthreads();

    float nh = 0.0f;
    #pragma unroll
    for (int k = 0; k < KNB; ++k)
        nh = fmaf(att_s[k], ent[(size_t)eid_s[k] * DIM + tid], nh);

    const float h = ent[(size_t)id * DIM + tid] * SCALE[id];
    U[(size_t)b * DIM + tid] = h + nh;
    V[(size_t)b * DIM + tid] = h * nh;
}

// ---------------------------------------------------------------------------
// Kernel C1: out = leaky(U @ W1^T + b1)      (readlane matvec, 8 rows/block)
// Kernel C2: out += leaky(V @ W2^T + b2)
// ---------------------------------------------------------------------------
#define OUT_ROWS 8

__global__ __launch_bounds__(128) void k_out1(
    const float* __restrict__ X, const float* __restrict__ W,
    const float* __restrict__ bias, float* __restrict__ out)
{
    const int tid = threadIdx.x, lane = tid & 63;
    float w[DIM];
    #pragma unroll
    for (int i = 0; i < DIM; ++i) w[i] = W[tid * DIM + i];
    const float bj = bias[tid];
    const int row0 = blockIdx.x * OUT_ROWS;
    for (int r = 0; r < OUT_ROWS; ++r) {
        const int row = row0 + r;
        const float xa = X[(size_t)row * DIM + lane];
        const float xb = X[(size_t)row * DIM + 64 + lane];
        float acc = bj;
        #pragma unroll
        for (int i = 0; i < 64; ++i) acc = fmaf(lane_bcast(xa, i), w[i], acc);
        #pragma unroll
        for (int i = 0; i < 64; ++i) acc = fmaf(lane_bcast(xb, i), w[64 + i], acc);
        out[(size_t)row * DIM + tid] = acc > 0.0f ? acc : 0.2f * acc;
    }
}

__global__ __launch_bounds__(128) void k_out2(
    const float* __restrict__ X, const float* __restrict__ W,
    const float* __restrict__ bias, float* __restrict__ out)
{
    const int tid = threadIdx.x, lane = tid & 63;
    float w[DIM];
    #pragma unroll
    for (int i = 0; i < DIM; ++i) w[i] = W[tid * DIM + i];
    const float bj = bias[tid];
    const int row0 = blockIdx.x * OUT_ROWS;
    for (int r = 0; r < OUT_ROWS; ++r) {
        const int row = row0 + r;
        const float xa = X[(size_t)row * DIM + lane];
        const float xb = X[(size_t)row * DIM + 64 + lane];
        float acc = bj;
        #pragma unroll
        for (int i = 0; i < 64; ++i) acc = fmaf(lane_bcast(xa, i), w[i], acc);
        #pragma unroll
        for (int i = 0; i < 64; ++i) acc = fmaf(lane_bcast(xb, i), w[64 + i], acc);
        const float l = acc > 0.0f ? acc : 0.2f * acc;
        out[(size_t)row * DIM + tid] += l;
    }
}

extern "C" void kernel_launch(void* const* d_in, const int* in_sizes, int n_in,
                              void* d_out, int out_size, void* d_ws, size_t ws_size,
                              hipStream_t stream) {
    (void)in_sizes; (void)n_in; (void)out_size; (void)ws_size;
    const int*   idx     = (const int*)d_in[0];
    const int*   adj_ent = (const int*)d_in[1];
    const int*   adj_rel = (const int*)d_in[2];
    const float* ent     = (const float*)d_in[3];
    const float* rel     = (const float*)d_in[4];
    const float* Wr_w    = (const float*)d_in[5];
    const float* Wr_b    = (const float*)d_in[6];
    const float* W1_w    = (const float*)d_in[7];
    const float* W1_b    = (const float*)d_in[8];
    const float* W2_w    = (const float*)d_in[9];
    const float* W2_b    = (const float*)d_in[10];
    float* out = (float*)d_out;

    char* ws = (char*)d_ws;
    // workspace layout (bytes):
    // ENT_TR 51.2MB | SCALE 0.4MB | REL_N 32KB | U 8.39MB | V 8.39MB | scores 2.1MB
    float* ENT_TR = (float*)(ws);
    float* SCALE  = (float*)(ws + 51200000);
    float* REL_N  = (float*)(ws + 51600000);
    float* U      = (float*)(ws + 51632768);
    float* V      = (float*)(ws + 60021376);
    float* SC     = (float*)(ws + 68409984);

    k_ent_pre<<<dim3(N_ENT / 32), dim3(128), 0, stream>>>(ent, Wr_w, Wr_b, ENT_TR, SCALE);
    k_rel_pre<<<dim3(N_REL), dim3(128), 0, stream>>>(rel, REL_N);
    k_score<<<dim3(BATCH * KNB / 4), dim3(256), 0, stream>>>(idx, adj_ent, adj_rel,
                                                             ENT_TR, REL_N, SC);
    k_agg<<<dim3(BATCH), dim3(128), 0, stream>>>(idx, adj_ent, ent, SCALE, SC, U, V);
    k_out1<<<dim3(BATCH / OUT_ROWS), dim3(128), 0, stream>>>(U, W1_w, W1_b, out);
    k_out2<<<dim3(BATCH / OUT_ROWS), dim3(128), 0, stream>>>(V, W2_w, W2_b, out);
}

// Round 3
// 305.748 us; speedup vs baseline: 2.0071x; 1.5474x over previous
//
#include <hip/hip_runtime.h>
#include <math.h>

#define N_ENT 100000
#define N_REL 64
#define DIM   128
#define KNB   32
#define BATCH 16384

__device__ __forceinline__ int clamp_id(int id) {
    return id < 0 ? 0 : (id > N_ENT - 1 ? N_ENT - 1 : id);
}

// ---------------------------------------------------------------------------
// Kernel T: transpose 128x128 weight matrices to [i][j] layout (3 matrices)
// ---------------------------------------------------------------------------
__global__ __launch_bounds__(256) void k_transpose(
    const float* __restrict__ Wr, const float* __restrict__ W1,
    const float* __restrict__ W2, float* __restrict__ Wrt,
    float* __restrict__ W1t, float* __restrict__ W2t)
{
    const int m = blockIdx.x >> 6;           // 0,1,2
    const int f = (blockIdx.x & 63) * 256 + threadIdx.x;  // 0..16383
    const int i = f >> 7, j = f & 127;
    const float* W  = m == 0 ? Wr  : (m == 1 ? W1  : W2);
    float*       Wt = m == 0 ? Wrt : (m == 1 ? W1t : W2t);
    Wt[i * DIM + j] = W[j * DIM + i];
}

// ---------------------------------------------------------------------------
// Kernel A: ENT_TR[e][j] = maxnorm(ent[e]) @ Wr^T + Wr_b ; SCALE[e]
// lanes = rows (64 rows/block), 4 waves each own a 32-wide j chunk.
// Weights streamed from SGPRs (uniform loads from transposed Wrt).
// ---------------------------------------------------------------------------
#define EP_STRIDE 132   // floats; 528B row stride: 16B aligned, even bank spread

__global__ __launch_bounds__(256) void k_ent_pre(
    const float* __restrict__ ent, const float* __restrict__ Wt,
    const float* __restrict__ Wrb, float* __restrict__ ENT_TR,
    float* __restrict__ SCALE)
{
    __shared__ float xs[64 * EP_STRIDE];

    const int row0 = blockIdx.x * 64;
    // stage 64 rows x 128 floats, coalesced float4
    for (int it = 0; it < 8; ++it) {
        const int f = it * 256 + threadIdx.x;      // 0..2047 float4 slots
        const int r = f >> 5, c4 = f & 31;
        const int rg = min(row0 + r, N_ENT - 1);
        const float4 v = *(const float4*)(ent + (size_t)rg * DIM + c4 * 4);
        *(float4*)(xs + r * EP_STRIDE + c4 * 4) = v;
    }
    __syncthreads();

    const int lane = threadIdx.x & 63;              // row within tile
    const int wid  = threadIdx.x >> 6;              // 0..3
    const int j0   = __builtin_amdgcn_readfirstlane(wid * 32);

    float acc[32];
    #pragma unroll
    for (int jj = 0; jj < 32; ++jj) acc[jj] = 0.0f;
    float ss = 0.0f;

    const float* xrow = xs + lane * EP_STRIDE;
    for (int i4 = 0; i4 < 32; ++i4) {
        const float4 xv = *(const float4*)(xrow + i4 * 4);
        ss = fmaf(xv.x, xv.x, ss); ss = fmaf(xv.y, xv.y, ss);
        ss = fmaf(xv.z, xv.z, ss); ss = fmaf(xv.w, xv.w, ss);
        #pragma unroll
        for (int d = 0; d < 4; ++d) {
            const float xi = d == 0 ? xv.x : (d == 1 ? xv.y : (d == 2 ? xv.z : xv.w));
            const float* __restrict__ wrow = Wt + (i4 * 4 + d) * DIM + j0;  // uniform -> s_load
            #pragma unroll
            for (int jj = 0; jj < 32; ++jj)
                acc[jj] = fmaf(xi, wrow[jj], acc[jj]);
        }
    }

    const float s = fminf(1.0f, 1.0f / fmaxf(sqrtf(ss), 1e-12f));
    const int row = row0 + lane;
    if (row < N_ENT) {
        if (wid == 0) SCALE[row] = s;
        const float* __restrict__ bp = Wrb + j0;    // uniform
        #pragma unroll
        for (int q = 0; q < 8; ++q) {
            float4 o;
            o.x = fmaf(acc[4 * q + 0], s, bp[4 * q + 0]);
            o.y = fmaf(acc[4 * q + 1], s, bp[4 * q + 1]);
            o.z = fmaf(acc[4 * q + 2], s, bp[4 * q + 2]);
            o.w = fmaf(acc[4 * q + 3], s, bp[4 * q + 3]);
            *(float4*)(ENT_TR + (size_t)row * DIM + j0 + 4 * q) = o;
        }
    }
}

// ---------------------------------------------------------------------------
// Kernel A2: REL_N = maxnorm(rel_table) (64 rows)
// ---------------------------------------------------------------------------
__global__ __launch_bounds__(128) void k_rel_pre(
    const float* __restrict__ rel, float* __restrict__ REL_N)
{
    __shared__ float part[2];
    const int row = blockIdx.x, tid = threadIdx.x;
    const float x = rel[row * DIM + tid];
    float ss = x * x;
    #pragma unroll
    for (int m = 1; m < 64; m <<= 1) ss += __shfl_xor(ss, m);
    if ((tid & 63) == 0) part[tid >> 6] = ss;
    __syncthreads();
    const float tot = part[0] + part[1];
    const float s = fminf(1.0f, 1.0f / fmaxf(sqrtf(tot), 1e-12f));
    REL_N[row * DIM + tid] = x * s;
}

// ---------------------------------------------------------------------------
// Kernel B1: scores. One wave per batch element; hr register-resident,
// loop over 32 neighbors with ids broadcast via shfl.
// ---------------------------------------------------------------------------
__global__ __launch_bounds__(256) void k_score(
    const int* __restrict__ idx, const int* __restrict__ adj_ent,
    const int* __restrict__ adj_rel, const float* __restrict__ ENT_TR,
    const float* __restrict__ REL_N, float* __restrict__ scores)
{
    const int wid  = threadIdx.x >> 6;
    const int lane = threadIdx.x & 63;
    const int b = blockIdx.x * 4 + wid;

    const int id = clamp_id(idx[b]);
    const float hr0 = ENT_TR[(size_t)id * DIM + lane];
    const float hr1 = ENT_TR[(size_t)id * DIM + 64 + lane];
    const int eL = adj_ent[(size_t)id * KNB + (lane & 31)];
    const int rL = adj_rel[(size_t)id * KNB + (lane & 31)];

    float myscore = 0.0f;
    #pragma unroll 4
    for (int k = 0; k < KNB; ++k) {
        const int e = __shfl(eL, k);
        const int r = __shfl(rL, k);
        const float* __restrict__ tr = ENT_TR + (size_t)e * DIM;
        const float* __restrict__ rn = REL_N + r * DIM;
        float s = tanhf(hr0 + rn[lane]) * tr[lane]
                + tanhf(hr1 + rn[64 + lane]) * tr[64 + lane];
        #pragma unroll
        for (int m = 1; m < 64; m <<= 1) s += __shfl_xor(s, m);
        if (lane == k) myscore = s;
    }
    if (lane < KNB) scores[b * KNB + lane] = myscore;
}

// ---------------------------------------------------------------------------
// Kernel B2: softmax over k + Nh aggregate + U/V. One 128-thread block per b.
// ---------------------------------------------------------------------------
__global__ __launch_bounds__(128) void k_agg(
    const int* __restrict__ idx, const int* __restrict__ adj_ent,
    const float* __restrict__ ent, const float* __restrict__ SCALE,
    const float* __restrict__ scores, float* __restrict__ U,
    float* __restrict__ V)
{
    __shared__ float att_s[KNB];
    __shared__ int   eid_s[KNB];

    const int b = blockIdx.x;
    const int tid = threadIdx.x;
    const int id = clamp_id(idx[b]);

    if (tid < KNB) {
        const float s = scores[b * KNB + tid];
        float m = s;
        #pragma unroll
        for (int mk = 1; mk < 32; mk <<= 1) m = fmaxf(m, __shfl_xor(m, mk));
        const float e = expf(s - m);
        float t = e;
        #pragma unroll
        for (int mk = 1; mk < 32; mk <<= 1) t += __shfl_xor(t, mk);
        const int eid = adj_ent[(size_t)id * KNB + tid];
        att_s[tid] = (e / t) * SCALE[eid];
        eid_s[tid] = eid;
    }
    __syncthreads();

    float nh = 0.0f;
    #pragma unroll
    for (int k = 0; k < KNB; ++k)
        nh = fmaf(att_s[k], ent[(size_t)eid_s[k] * DIM + tid], nh);

    const float h = ent[(size_t)id * DIM + tid] * SCALE[id];
    U[(size_t)b * DIM + tid] = h + nh;
    V[(size_t)b * DIM + tid] = h * nh;
}

// ---------------------------------------------------------------------------
// Kernel C: out = leaky(U @ W1^T + b1) + leaky(V @ W2^T + b2), fused.
// lanes = rows (64 rows/block), 8 waves each own a 16-wide j chunk.
// ---------------------------------------------------------------------------
__global__ __launch_bounds__(512) void k_out(
    const float* __restrict__ U, const float* __restrict__ V,
    const float* __restrict__ W1t, const float* __restrict__ b1,
    const float* __restrict__ W2t, const float* __restrict__ b2,
    float* __restrict__ out)
{
    __shared__ float us[64 * EP_STRIDE];
    __shared__ float vs[64 * EP_STRIDE];

    const int row0 = blockIdx.x * 64;
    for (int it = 0; it < 4; ++it) {
        const int f = it * 512 + threadIdx.x;       // 0..2047
        const int r = f >> 5, c4 = f & 31;
        *(float4*)(us + r * EP_STRIDE + c4 * 4) =
            *(const float4*)(U + (size_t)(row0 + r) * DIM + c4 * 4);
        *(float4*)(vs + r * EP_STRIDE + c4 * 4) =
            *(const float4*)(V + (size_t)(row0 + r) * DIM + c4 * 4);
    }
    __syncthreads();

    const int lane = threadIdx.x & 63;              // row within tile
    const int wid  = threadIdx.x >> 6;              // 0..7
    const int j0   = __builtin_amdgcn_readfirstlane(wid * 16);

    float accU[16], accV[16];
    #pragma unroll
    for (int jj = 0; jj < 16; ++jj) { accU[jj] = 0.0f; accV[jj] = 0.0f; }

    const float* urow = us + lane * EP_STRIDE;
    const float* vrow = vs + lane * EP_STRIDE;
    for (int i4 = 0; i4 < 32; ++i4) {
        const float4 uv = *(const float4*)(urow + i4 * 4);
        const float4 vv = *(const float4*)(vrow + i4 * 4);
        #pragma unroll
        for (int d = 0; d < 4; ++d) {
            const float ui = d == 0 ? uv.x : (d == 1 ? uv.y : (d == 2 ? uv.z : uv.w));
            const float vi = d == 0 ? vv.x : (d == 1 ? vv.y : (d == 2 ? vv.z : vv.w));
            const float* __restrict__ w1r = W1t + (i4 * 4 + d) * DIM + j0;  // uniform
            const float* __restrict__ w2r = W2t + (i4 * 4 + d) * DIM + j0;  // uniform
            #pragma unroll
            for (int jj = 0; jj < 16; ++jj) {
                accU[jj] = fmaf(ui, w1r[jj], accU[jj]);
                accV[jj] = fmaf(vi, w2r[jj], accV[jj]);
            }
        }
    }

    const int row = row0 + lane;
    const float* __restrict__ b1p = b1 + j0;
    const float* __restrict__ b2p = b2 + j0;
    #pragma unroll
    for (int q = 0; q < 4; ++q) {
        float4 o;
        #pragma unroll
        for (int d = 0; d < 4; ++d) {
            const int jj = 4 * q + d;
            const float a = accU[jj] + b1p[jj];
            const float c = accV[jj] + b2p[jj];
            const float la = a > 0.0f ? a : 0.2f * a;
            const float lc = c > 0.0f ? c : 0.2f * c;
            ((float*)&o)[d] = la + lc;
        }
        *(float4*)(out + (size_t)row * DIM + j0 + 4 * q) = o;
    }
}

extern "C" void kernel_launch(void* const* d_in, const int* in_sizes, int n_in,
                              void* d_out, int out_size, void* d_ws, size_t ws_size,
                              hipStream_t stream) {
    (void)in_sizes; (void)n_in; (void)out_size; (void)ws_size;
    const int*   idx     = (const int*)d_in[0];
    const int*   adj_ent = (const int*)d_in[1];
    const int*   adj_rel = (const int*)d_in[2];
    const float* ent     = (const float*)d_in[3];
    const float* rel     = (const float*)d_in[4];
    const float* Wr_w    = (const float*)d_in[5];
    const float* Wr_b    = (const float*)d_in[6];
    const float* W1_w    = (const float*)d_in[7];
    const float* W1_b    = (const float*)d_in[8];
    const float* W2_w    = (const float*)d_in[9];
    const float* W2_b    = (const float*)d_in[10];
    float* out = (float*)d_out;

    char* ws = (char*)d_ws;
    // workspace layout (bytes):
    float* ENT_TR = (float*)(ws);               // 51,200,000
    float* SCALE  = (float*)(ws + 51200000);    //    400,000
    float* REL_N  = (float*)(ws + 51600000);    //     32,768
    float* U      = (float*)(ws + 51632768);    //  8,388,608
    float* V      = (float*)(ws + 60021376);    //  8,388,608
    float* SC     = (float*)(ws + 68409984);    //  2,097,152
    float* Wrt    = (float*)(ws + 70507136);    //     65,536
    float* W1t    = (float*)(ws + 70572672);    //     65,536
    float* W2t    = (float*)(ws + 70638208);    //     65,536  (total 70,703,744)

    k_transpose<<<dim3(192), dim3(256), 0, stream>>>(Wr_w, W1_w, W2_w, Wrt, W1t, W2t);
    k_rel_pre<<<dim3(N_REL), dim3(128), 0, stream>>>(rel, REL_N);
    k_ent_pre<<<dim3((N_ENT + 63) / 64), dim3(256), 0, stream>>>(ent, Wrt, Wr_b,
                                                                 ENT_TR, SCALE);
    k_score<<<dim3(BATCH / 4), dim3(256), 0, stream>>>(idx, adj_ent, adj_rel,
                                                       ENT_TR, REL_N, SC);
    k_agg<<<dim3(BATCH), dim3(128), 0, stream>>>(idx, adj_ent, ent, SCALE, SC, U, V);
    k_out<<<dim3(BATCH / 64), dim3(512), 0, stream>>>(U, V, W1t, W1_b, W2t, W2_b, out);
}

// Round 4
// 288.027 us; speedup vs baseline: 2.1306x; 1.0615x over previous
//
#include <hip/hip_runtime.h>
#include <math.h>

#define N_ENT 100000
#define N_REL 64
#define DIM   128
#define KNB   32
#define BATCH 16384

__device__ __forceinline__ int clamp_id(int id) {
    return id < 0 ? 0 : (id > N_ENT - 1 ? N_ENT - 1 : id);
}

// tanh(x) = 1 - 2/(exp(2x)+1); v_mul+v_exp+v_add+v_rcp+v_fma (~5 ops, err ~1e-6)
__device__ __forceinline__ float fast_tanh(float x) {
    const float e = __expf(2.0f * x);
    return 1.0f - 2.0f * __builtin_amdgcn_rcpf(e + 1.0f);
}

// ---------------------------------------------------------------------------
// Kernel T: transpose 128x128 weight matrices to [i][j] layout (3 matrices)
// ---------------------------------------------------------------------------
__global__ __launch_bounds__(256) void k_transpose(
    const float* __restrict__ Wr, const float* __restrict__ W1,
    const float* __restrict__ W2, float* __restrict__ Wrt,
    float* __restrict__ W1t, float* __restrict__ W2t)
{
    const int m = blockIdx.x >> 6;           // 0,1,2
    const int f = (blockIdx.x & 63) * 256 + threadIdx.x;  // 0..16383
    const int i = f >> 7, j = f & 127;
    const float* W  = m == 0 ? Wr  : (m == 1 ? W1  : W2);
    float*       Wt = m == 0 ? Wrt : (m == 1 ? W1t : W2t);
    Wt[i * DIM + j] = W[j * DIM + i];
}

// ---------------------------------------------------------------------------
// Kernel A2: REL_N = maxnorm(rel_table) (64 rows)
// ---------------------------------------------------------------------------
__global__ __launch_bounds__(128) void k_rel_pre(
    const float* __restrict__ rel, float* __restrict__ REL_N)
{
    __shared__ float part[2];
    const int row = blockIdx.x, tid = threadIdx.x;
    const float x = rel[row * DIM + tid];
    float ss = x * x;
    #pragma unroll
    for (int m = 1; m < 64; m <<= 1) ss += __shfl_xor(ss, m);
    if ((tid & 63) == 0) part[tid >> 6] = ss;
    __syncthreads();
    const float tot = part[0] + part[1];
    const float s = fminf(1.0f, 1.0f / fmaxf(sqrtf(tot), 1e-12f));
    REL_N[row * DIM + tid] = x * s;
}

// ---------------------------------------------------------------------------
// Kernel A: ENT_TR[e][j] = maxnorm(ent[e]) @ Wr^T + Wr_b ; SCALE[e]
// lanes = rows (64 rows/block, direct global loads, no LDS),
// 4 waves each own a 32-wide j chunk; weights via uniform (scalar) loads.
// ---------------------------------------------------------------------------
__global__ __launch_bounds__(256) void k_ent_pre(
    const float* __restrict__ ent, const float* __restrict__ Wt,
    const float* __restrict__ Wrb, float* __restrict__ ENT_TR,
    float* __restrict__ SCALE)
{
    const int lane = threadIdx.x & 63;
    const int wid  = threadIdx.x >> 6;              // 0..3
    const int j0   = __builtin_amdgcn_readfirstlane(wid * 32);
    const int row  = min(blockIdx.x * 64 + lane, N_ENT - 1);
    const float* __restrict__ xrow = ent + (size_t)row * DIM;

    float acc[32];
    #pragma unroll
    for (int jj = 0; jj < 32; ++jj) acc[jj] = 0.0f;
    float ss = 0.0f;

    float4 xv = *(const float4*)(xrow);
    #pragma unroll 2
    for (int i4 = 0; i4 < 32; ++i4) {
        const float4 cur = xv;
        if (i4 < 31) xv = *(const float4*)(xrow + (i4 + 1) * 4);
        ss = fmaf(cur.x, cur.x, ss); ss = fmaf(cur.y, cur.y, ss);
        ss = fmaf(cur.z, cur.z, ss); ss = fmaf(cur.w, cur.w, ss);
        #pragma unroll
        for (int d = 0; d < 4; ++d) {
            const float xi = d == 0 ? cur.x : (d == 1 ? cur.y : (d == 2 ? cur.z : cur.w));
            const float* __restrict__ wrow = Wt + (i4 * 4 + d) * DIM + j0;  // uniform
            #pragma unroll
            for (int jj = 0; jj < 32; ++jj)
                acc[jj] = fmaf(xi, wrow[jj], acc[jj]);
        }
    }

    const float s = fminf(1.0f, 1.0f / fmaxf(sqrtf(ss), 1e-12f));
    if (wid == 0) SCALE[row] = s;
    const float* __restrict__ bp = Wrb + j0;        // uniform
    #pragma unroll
    for (int q = 0; q < 8; ++q) {
        float4 o;
        o.x = fmaf(acc[4 * q + 0], s, bp[4 * q + 0]);
        o.y = fmaf(acc[4 * q + 1], s, bp[4 * q + 1]);
        o.z = fmaf(acc[4 * q + 2], s, bp[4 * q + 2]);
        o.w = fmaf(acc[4 * q + 3], s, bp[4 * q + 3]);
        *(float4*)(ENT_TR + (size_t)row * DIM + j0 + 4 * q) = o;
    }
}

// ---------------------------------------------------------------------------
// Kernel B: fused score + softmax + aggregate. One wave per batch element.
// Phase 1: score_k = sum_j tanh(hr[j]+rn[j])*tr[j]  (fast tanh)
// Phase 2: in-wave softmax over k (lanes 0..31)
// Phase 3: Nh = sum_k att_k * scale_k * ent[e_k]; U = h+Nh, V = h*Nh
// ---------------------------------------------------------------------------
__global__ __launch_bounds__(256) void k_sa(
    const int* __restrict__ idx, const int* __restrict__ adj_ent,
    const int* __restrict__ adj_rel, const float* __restrict__ ent,
    const float* __restrict__ ENT_TR, const float* __restrict__ SCALE,
    const float* __restrict__ REL_N, float* __restrict__ U,
    float* __restrict__ V)
{
    const int wid  = threadIdx.x >> 6;
    const int lane = threadIdx.x & 63;
    const int b = blockIdx.x * 4 + wid;

    const int id = clamp_id(idx[b]);
    const float hr0 = ENT_TR[(size_t)id * DIM + lane];
    const float hr1 = ENT_TR[(size_t)id * DIM + 64 + lane];
    const int eL = adj_ent[(size_t)id * KNB + (lane & 31)];
    const int rL = adj_rel[(size_t)id * KNB + (lane & 31)];
    const float sL = SCALE[eL];

    // phase 1: scores (lane k holds score_k for lane<32)
    float sc = 0.0f;
    #pragma unroll 4
    for (int k = 0; k < KNB; ++k) {
        const int e = __shfl(eL, k);
        const int r = __shfl(rL, k);
        const float* __restrict__ tr = ENT_TR + (size_t)e * DIM;
        const float* __restrict__ rn = REL_N + r * DIM;
        float s = fast_tanh(hr0 + rn[lane]) * tr[lane]
                + fast_tanh(hr1 + rn[64 + lane]) * tr[64 + lane];
        #pragma unroll
        for (int m = 1; m < 64; m <<= 1) s += __shfl_xor(s, m);
        if (lane == k) sc = s;
    }

    // phase 2: softmax over k within low 32 lanes (high lanes harmless)
    float mx = sc;
    #pragma unroll
    for (int m = 1; m < 32; m <<= 1) mx = fmaxf(mx, __shfl_xor(mx, m));
    const float ex = __expf(sc - mx);
    float tt = ex;
    #pragma unroll
    for (int m = 1; m < 32; m <<= 1) tt += __shfl_xor(tt, m);
    const float attL = ex * __builtin_amdgcn_rcpf(tt) * sL;

    // phase 3: aggregate
    float nh0 = 0.0f, nh1 = 0.0f;
    #pragma unroll 4
    for (int k = 0; k < KNB; ++k) {
        const float a = __shfl(attL, k);
        const int e = __shfl(eL, k);
        const float* __restrict__ tp = ent + (size_t)e * DIM;
        nh0 = fmaf(a, tp[lane], nh0);
        nh1 = fmaf(a, tp[64 + lane], nh1);
    }

    const float sid = SCALE[id];
    const float h0 = ent[(size_t)id * DIM + lane] * sid;
    const float h1 = ent[(size_t)id * DIM + 64 + lane] * sid;
    U[(size_t)b * DIM + lane]      = h0 + nh0;
    U[(size_t)b * DIM + 64 + lane] = h1 + nh1;
    V[(size_t)b * DIM + lane]      = h0 * nh0;
    V[(size_t)b * DIM + 64 + lane] = h1 * nh1;
}

// ---------------------------------------------------------------------------
// Kernel C: out = leaky(U @ W1^T + b1) + leaky(V @ W2^T + b2), fused.
// lanes = rows (64 rows/block, direct loads, no LDS); 8 waves x 16-j chunks.
// ---------------------------------------------------------------------------
__global__ __launch_bounds__(512) void k_out(
    const float* __restrict__ U, const float* __restrict__ V,
    const float* __restrict__ W1t, const float* __restrict__ b1,
    const float* __restrict__ W2t, const float* __restrict__ b2,
    float* __restrict__ out)
{
    const int lane = threadIdx.x & 63;
    const int wid  = threadIdx.x >> 6;              // 0..7
    const int j0   = __builtin_amdgcn_readfirstlane(wid * 16);
    const int row  = blockIdx.x * 64 + lane;
    const float* __restrict__ urow = U + (size_t)row * DIM;
    const float* __restrict__ vrow = V + (size_t)row * DIM;

    float accU[16], accV[16];
    #pragma unroll
    for (int jj = 0; jj < 16; ++jj) { accU[jj] = 0.0f; accV[jj] = 0.0f; }

    float4 uv = *(const float4*)(urow);
    float4 vv = *(const float4*)(vrow);
    #pragma unroll 2
    for (int i4 = 0; i4 < 32; ++i4) {
        const float4 cu = uv, cv = vv;
        if (i4 < 31) {
            uv = *(const float4*)(urow + (i4 + 1) * 4);
            vv = *(const float4*)(vrow + (i4 + 1) * 4);
        }
        #pragma unroll
        for (int d = 0; d < 4; ++d) {
            const float ui = d == 0 ? cu.x : (d == 1 ? cu.y : (d == 2 ? cu.z : cu.w));
            const float vi = d == 0 ? cv.x : (d == 1 ? cv.y : (d == 2 ? cv.z : cv.w));
            const float* __restrict__ w1r = W1t + (i4 * 4 + d) * DIM + j0;  // uniform
            const float* __restrict__ w2r = W2t + (i4 * 4 + d) * DIM + j0;  // uniform
            #pragma unroll
            for (int jj = 0; jj < 16; ++jj) {
                accU[jj] = fmaf(ui, w1r[jj], accU[jj]);
                accV[jj] = fmaf(vi, w2r[jj], accV[jj]);
            }
        }
    }

    const float* __restrict__ b1p = b1 + j0;
    const float* __restrict__ b2p = b2 + j0;
    #pragma unroll
    for (int q = 0; q < 4; ++q) {
        float4 o;
        #pragma unroll
        for (int d = 0; d < 4; ++d) {
            const int jj = 4 * q + d;
            const float a = accU[jj] + b1p[jj];
            const float c = accV[jj] + b2p[jj];
            const float la = a > 0.0f ? a : 0.2f * a;
            const float lc = c > 0.0f ? c : 0.2f * c;
            ((float*)&o)[d] = la + lc;
        }
        *(float4*)(out + (size_t)row * DIM + j0 + 4 * q) = o;
    }
}

extern "C" void kernel_launch(void* const* d_in, const int* in_sizes, int n_in,
                              void* d_out, int out_size, void* d_ws, size_t ws_size,
                              hipStream_t stream) {
    (void)in_sizes; (void)n_in; (void)out_size; (void)ws_size;
    const int*   idx     = (const int*)d_in[0];
    const int*   adj_ent = (const int*)d_in[1];
    const int*   adj_rel = (const int*)d_in[2];
    const float* ent     = (const float*)d_in[3];
    const float* rel     = (const float*)d_in[4];
    const float* Wr_w    = (const float*)d_in[5];
    const float* Wr_b    = (const float*)d_in[6];
    const float* W1_w    = (const float*)d_in[7];
    const float* W1_b    = (const float*)d_in[8];
    const float* W2_w    = (const float*)d_in[9];
    const float* W2_b    = (const float*)d_in[10];
    float* out = (float*)d_out;

    char* ws = (char*)d_ws;
    // workspace layout (bytes):
    float* ENT_TR = (float*)(ws);               // 51,200,000
    float* SCALE  = (float*)(ws + 51200000);    //    400,000
    float* REL_N  = (float*)(ws + 51600000);    //     32,768
    float* U      = (float*)(ws + 51632768);    //  8,388,608
    float* V      = (float*)(ws + 60021376);    //  8,388,608
    float* Wrt    = (float*)(ws + 68409984);    //     65,536
    float* W1t    = (float*)(ws + 68475520);    //     65,536
    float* W2t    = (float*)(ws + 68541056);    //     65,536  (total 68,606,592)

    k_transpose<<<dim3(192), dim3(256), 0, stream>>>(Wr_w, W1_w, W2_w, Wrt, W1t, W2t);
    k_rel_pre<<<dim3(N_REL), dim3(128), 0, stream>>>(rel, REL_N);
    k_ent_pre<<<dim3((N_ENT + 63) / 64), dim3(256), 0, stream>>>(ent, Wrt, Wr_b,
                                                                 ENT_TR, SCALE);
    k_sa<<<dim3(BATCH / 4), dim3(256), 0, stream>>>(idx, adj_ent, adj_rel, ent,
                                                    ENT_TR, SCALE, REL_N, U, V);
    k_out<<<dim3(BATCH / 64), dim3(512), 0, stream>>>(U, V, W1t, W1_b, W2t, W2_b, out);
}